// Round 8
// baseline (419.468 us; speedup 1.0000x reference)
//
#include <hip/hip_runtime.h>
#include <cstddef>
#include <cstdint>

// ---------------- types / helpers ----------------
typedef __attribute__((ext_vector_type(8))) short bh8_t;  // 8 bf16 (4 VGPRs)
typedef __attribute__((ext_vector_type(4))) float f4_t;   // MFMA accumulator

__device__ __forceinline__ unsigned short f2bf(float x) {
    union { float f; unsigned u; } v; v.f = x;
    unsigned r = v.u + 0x7fffu + ((v.u >> 16) & 1u);   // RN-even
    return (unsigned short)(r >> 16);
}
__device__ __forceinline__ float bf2f(unsigned short u) {
    union { unsigned u; float f; } v; v.u = ((unsigned)u) << 16;
    return v.f;
}

// async global->LDS, 16B per lane. dest = wave-uniform base + lane*16.
__device__ __forceinline__ void gl_lds16(const void* g, void* l) {
    __builtin_amdgcn_global_load_lds(
        (const __attribute__((address_space(1))) unsigned int*)g,
        (__attribute__((address_space(3))) unsigned int*)l, 16, 0, 0);
}

// Problem constants
#define B_    2
#define S_    2048
#define D_    2048
#define H_    16
#define HD_   128

// ---------------------------------------------------------------------------
// x (f32) -> bf16, same layout. 8 elems/thread.
// ---------------------------------------------------------------------------
__global__ __launch_bounds__(256) void cvt_f32_bf16(const float* __restrict__ in,
                                                    ushort* __restrict__ out) {
    size_t i = ((size_t)blockIdx.x * 256 + threadIdx.x) * 8;
    float4 a = *(const float4*)&in[i];
    float4 b = *(const float4*)&in[i + 4];
    ushort4 o0, o1;
    o0.x = f2bf(a.x); o0.y = f2bf(a.y); o0.z = f2bf(a.z); o0.w = f2bf(a.w);
    o1.x = f2bf(b.x); o1.y = f2bf(b.y); o1.z = f2bf(b.z); o1.w = f2bf(b.w);
    *(ushort4*)&out[i]     = o0;
    *(ushort4*)&out[i + 4] = o1;
}

// ---------------------------------------------------------------------------
// W[R][C] f32  ->  Wt[C][R] bf16   (64x64 LDS tile transpose)
// ---------------------------------------------------------------------------
__global__ __launch_bounds__(256) void transp_f32_bf16(const float* __restrict__ in,
                                                       ushort* __restrict__ out,
                                                       int R, int C) {
    __shared__ float T[64][68];
    const int t = threadIdx.x, rl = t >> 4, cl = t & 15;
    const int r0 = blockIdx.y * 64, c0 = blockIdx.x * 64;
    #pragma unroll
    for (int j = 0; j < 4; ++j) {
        int row = rl + 16 * j;
        float4 v = *(const float4*)&in[(size_t)(r0 + row) * C + c0 + cl * 4];
        *(float4*)&T[row][cl * 4] = v;
    }
    __syncthreads();
    #pragma unroll
    for (int j = 0; j < 4; ++j) {
        int row = rl + 16 * j;
        ushort4 o;
        o.x = f2bf(T[cl * 4 + 0][row]);
        o.y = f2bf(T[cl * 4 + 1][row]);
        o.z = f2bf(T[cl * 4 + 2][row]);
        o.w = f2bf(T[cl * 4 + 3][row]);
        *(ushort4*)&out[(size_t)(c0 + row) * R + r0 + cl * 4] = o;
    }
}

// ---------------------------------------------------------------------------
// QKV GEMM: C[4096][6144] = xb * wtb^T + bias. 128x128 tile, BK=32,
// DOUBLE-BUFFERED gl_lds prefetch + counted vmcnt(4) (T3 minimum-2-phase).
// Q,K -> head-major bf16; V -> Vtg (pre-transposed [bh][d][s'], pi-permuted).
// ---------------------------------------------------------------------------
__global__ __launch_bounds__(256) void qkv_gemm(const ushort* __restrict__ A,
                                                const ushort* __restrict__ Bt,
                                                const float* __restrict__ bias,
                                                ushort* __restrict__ Qb,
                                                ushort* __restrict__ Kb,
                                                ushort* __restrict__ Vtg) {
    __shared__ ushort Al[2][128 * 32];
    __shared__ ushort Bl[2][128 * 32];
    const int tid = threadIdx.x;
    const int l = tid & 63, wv = tid >> 6;
    const int lr = l & 15, bk = l >> 4;
    const int wr = wv >> 1, wc = wv & 1;
    const int row0 = blockIdx.x * 128, col0 = blockIdx.y * 128;

    f4_t zero4 = {0.f, 0.f, 0.f, 0.f};
    f4_t acc[4][4];
    #pragma unroll
    for (int i = 0; i < 4; ++i)
        #pragma unroll
        for (int j = 0; j < 4; ++j) acc[i][j] = zero4;

    const int c0 = tid, c1 = tid + 256;         // 16B chunk ids (512 per tile)
    const ushort* Ap0 = A  + (size_t)(row0 + (c0 >> 2)) * 2048 + (c0 & 3) * 8;
    const ushort* Ap1 = A  + (size_t)(row0 + (c1 >> 2)) * 2048 + (c1 & 3) * 8;
    const ushort* Bp0 = Bt + (size_t)(col0 + (c0 >> 2)) * 2048 + (c0 & 3) * 8;
    const ushort* Bp1 = Bt + (size_t)(col0 + (c1 >> 2)) * 2048 + (c1 & 3) * 8;
    const int d0 = (c0 - l) * 8, d1 = (c1 - l) * 8;

    auto issue = [&](int k0, int buf) {
        gl_lds16(Ap0 + k0, &Al[buf][d0]);
        gl_lds16(Ap1 + k0, &Al[buf][d1]);
        gl_lds16(Bp0 + k0, &Bl[buf][d0]);
        gl_lds16(Bp1 + k0, &Bl[buf][d1]);
    };

    issue(0, 0);
    for (int k0 = 0; k0 < 2048; k0 += 32) {
        const int buf = (k0 >> 5) & 1;
        if (k0 + 32 < 2048) {
            issue(k0 + 32, buf ^ 1);
            asm volatile("s_waitcnt vmcnt(4)" ::: "memory");
        } else {
            asm volatile("s_waitcnt vmcnt(0)" ::: "memory");
        }
        __builtin_amdgcn_s_barrier();
        asm volatile("" ::: "memory");
        bh8_t af[4], bf[4];
        #pragma unroll
        for (int mf = 0; mf < 4; ++mf)
            af[mf] = *(const bh8_t*)&Al[buf][(wr * 64 + mf * 16 + lr) * 32 + bk * 8];
        #pragma unroll
        for (int nf = 0; nf < 4; ++nf)
            bf[nf] = *(const bh8_t*)&Bl[buf][(wc * 64 + nf * 16 + lr) * 32 + bk * 8];
        __builtin_amdgcn_s_setprio(1);
        #pragma unroll
        for (int mf = 0; mf < 4; ++mf)
            #pragma unroll
            for (int nf = 0; nf < 4; ++nf)
                acc[mf][nf] = __builtin_amdgcn_mfma_f32_16x16x32_bf16(
                    af[mf], bf[nf], acc[mf][nf], 0, 0, 0);
        __builtin_amdgcn_s_setprio(0);
        asm volatile("" ::: "memory");
        __builtin_amdgcn_s_barrier();
        asm volatile("" ::: "memory");
    }

    const int which = col0 >> 11;
    const int h = (col0 & 2047) >> 7;
    if (which < 2) {
        ushort* dst = which == 0 ? Qb : Kb;
        #pragma unroll
        for (int nf = 0; nf < 4; ++nf) {
            int n = col0 + wc * 64 + nf * 16 + lr;
            float bv = bias[n];
            int hd = (n & 2047) & 127;
            #pragma unroll
            for (int mf = 0; mf < 4; ++mf) {
                int mbase = row0 + wr * 64 + mf * 16 + bk * 4;
                #pragma unroll
                for (int r = 0; r < 4; ++r) {
                    int m = mbase + r;
                    int b = m >> 11, s = m & 2047;
                    dst[((size_t)(b * 16 + h) * 2048 + s) * 128 + hd] =
                        f2bf(acc[mf][nf][r] + bv);
                }
            }
        }
    } else {
        // V: write transposed+permuted: Vtg[(b*16+h)*128+hd][spos], 8B stores
        #pragma unroll
        for (int nf = 0; nf < 4; ++nf) {
            int n = col0 + wc * 64 + nf * 16 + lr;
            float bv = bias[n];
            int hd = n & 127;
            #pragma unroll
            for (int mf = 0; mf < 4; ++mf) {
                int mbase = row0 + wr * 64 + mf * 16 + bk * 4;
                int b = mbase >> 11, s4 = mbase & 2047;
                int spos = (s4 & ~31) | (((s4 >> 2) & 3) << 3) | (((s4 >> 4) & 1) << 2);
                ushort4 o;
                o.x = f2bf(acc[mf][nf][0] + bv);
                o.y = f2bf(acc[mf][nf][1] + bv);
                o.z = f2bf(acc[mf][nf][2] + bv);
                o.w = f2bf(acc[mf][nf][3] + bv);
                *(ushort4*)&Vtg[((size_t)((b * 16 + h) * 128 + hd)) * 2048 + spos] = o;
            }
        }
    }
}

// ---------------------------------------------------------------------------
// RoPE in place on bf16 Qb/Kb. Q pre-scaled by 1/sqrt(128).
// ---------------------------------------------------------------------------
__global__ __launch_bounds__(256) void rope_bf16(ushort* __restrict__ Qb,
                                                 ushort* __restrict__ Kb,
                                                 const float* __restrict__ cosn,
                                                 const float* __restrict__ sinn) {
    unsigned idx = blockIdx.x * 256 + threadIdx.x;
    int regn = idx >> 20;
    unsigned rest = idx & 1048575u;
    unsigned row = rest >> 4;
    int g = rest & 15;
    int s = row & 2047;
    ushort* base = (regn ? Kb : Qb) + (size_t)row * 128 + g * 4;
    uint2 lo = *(const uint2*)base;
    uint2 hi = *(const uint2*)(base + 64);
    float4 c4 = *(const float4*)&cosn[s * 128 + g * 4];
    float4 s4 = *(const float4*)&sinn[s * 128 + g * 4];
    const float sc = regn ? 1.0f : 0.08838834764831845f;
    const ushort* lp = (const ushort*)&lo;
    const ushort* hp = (const ushort*)&hi;
    float cf[4] = {c4.x, c4.y, c4.z, c4.w};
    float sf[4] = {s4.x, s4.y, s4.z, s4.w};
    ushort4 olo, ohi;
    ushort* olp = (ushort*)&olo;
    ushort* ohp = (ushort*)&ohi;
    #pragma unroll
    for (int e = 0; e < 4; ++e) {
        float lv = bf2f(lp[e]), hv = bf2f(hp[e]);
        olp[e] = f2bf((lv * cf[e] - hv * sf[e]) * sc);
        ohp[e] = f2bf((hv * cf[e] + lv * sf[e]) * sc);
    }
    *(ushort4*)base        = olo;
    *(ushort4*)(base + 64) = ohi;
}

// ---------------------------------------------------------------------------
// Flash attention v3: 128 q-rows/block (512 thr, 8 waves of 16 rows each),
// gl_lds staging (pre-swizzled source), double-buffered K/V, vmcnt(4),
// setprio, masked-tile skip for lower waves.
// K LDS: [key][128] ^((key&7)<<4).  V LDS: [d][64pos] ^((d&7)<<4), pos=pi(key).
// ---------------------------------------------------------------------------
__global__ __launch_bounds__(512) void attn3(const ushort* __restrict__ Qb,
                                             const ushort* __restrict__ Kb,
                                             const ushort* __restrict__ Vtg,
                                             ushort* __restrict__ AO) {
    __shared__ ushort lds[2][16384];   // per buf: K 8192 ushorts + V 8192
    const int tid = threadIdx.x;
    const int l = tid & 63, wq = tid >> 6;          // 8 waves
    const int lr = l & 15, bk = l >> 4;
    const int id = blockIdx.x;                      // 512 blocks
    const int bh = id & 31;                         // id%8 == bh%8 -> same XCD
    const int qb2 = 15 - (id >> 5);                 // heavy blocks first
    const int q0 = qb2 * 128;
    const int qrow = q0 + wq * 16 + lr;
    const ushort* Qg = Qb + ((size_t)bh * 2048 + qrow) * 128;
    const ushort* KgB = Kb + (size_t)bh * 2048 * 128;
    const ushort* VgB = Vtg + (size_t)bh * 128 * 2048;

    bh8_t qf[4];
    #pragma unroll
    for (int ks = 0; ks < 4; ++ks)
        qf[ks] = *(const bh8_t*)(Qg + ks * 32 + bk * 8);

    float mrun = -1e30f, lrun = 0.f;
    f4_t zero4 = {0.f, 0.f, 0.f, 0.f};
    f4_t oacc[8];
    #pragma unroll
    for (int i = 0; i < 8; ++i) oacc[i] = zero4;

    auto issue = [&](int kt, int buf) {
        ushort* Kl = &lds[buf][0];
        ushort* Vl = &lds[buf][8192];
        const ushort* Kg = KgB + (size_t)kt * 64 * 128;
        #pragma unroll
        for (int i = 0; i < 2; ++i) {
            int c = tid + 512 * i;                  // 0..1023
            int key = c >> 4, d8 = (c & 15) ^ (key & 7);
            gl_lds16(Kg + key * 128 + d8 * 8, Kl + (size_t)(c - l) * 8);
        }
        #pragma unroll
        for (int i = 0; i < 2; ++i) {
            int c = tid + 512 * i;
            int d = c >> 3, p8 = (c & 7) ^ (d & 7);
            gl_lds16(VgB + (size_t)d * 2048 + kt * 64 + p8 * 8,
                     Vl + (size_t)(c - l) * 8);
        }
    };

    const int nkt = 2 * qb2 + 2;                    // K tiles for this block
    issue(0, 0);
    for (int kt = 0; kt < nkt; ++kt) {
        const int buf = kt & 1;
        if (kt + 1 < nkt) {
            issue(kt + 1, buf ^ 1);
            asm volatile("s_waitcnt vmcnt(4)" ::: "memory");
        } else {
            asm volatile("s_waitcnt vmcnt(0)" ::: "memory");
        }
        __builtin_amdgcn_s_barrier();
        asm volatile("" ::: "memory");

        // wave-uniform: skip tiles fully above this wave's diagonal
        if (kt * 64 <= q0 + wq * 16 + 15) {
            const char* Kl = (const char*)&lds[buf][0];
            const char* Vl = (const char*)&lds[buf][8192];

            // ---- S^T = K * Q^T ----
            f4_t sacc[4];
            #pragma unroll
            for (int kf = 0; kf < 4; ++kf) sacc[kf] = zero4;
            __builtin_amdgcn_s_setprio(1);
            #pragma unroll
            for (int ks = 0; ks < 4; ++ks)
                #pragma unroll
                for (int kf = 0; kf < 4; ++kf) {
                    int key = kf * 16 + lr;
                    int ab = (key * 256 + ks * 64 + bk * 16) ^ ((key & 7) << 4);
                    bh8_t kv = *(const bh8_t*)(Kl + ab);
                    sacc[kf] = __builtin_amdgcn_mfma_f32_16x16x32_bf16(
                        kv, qf[ks], sacc[kf], 0, 0, 0);
                }
            __builtin_amdgcn_s_setprio(0);

            // causal mask when tile may cross this wave's diagonal
            if (kt * 64 + 63 > q0 + wq * 16) {
                #pragma unroll
                for (int kf = 0; kf < 4; ++kf)
                    #pragma unroll
                    for (int r = 0; r < 4; ++r) {
                        int key = kt * 64 + kf * 16 + bk * 4 + r;
                        if (key > qrow) sacc[kf][r] = -1e30f;
                    }
            }
            // ---- online softmax ----
            float mt = -1e30f;
            #pragma unroll
            for (int kf = 0; kf < 4; ++kf)
                #pragma unroll
                for (int r = 0; r < 4; ++r) mt = fmaxf(mt, sacc[kf][r]);
            mt = fmaxf(mt, __shfl_xor(mt, 16));
            mt = fmaxf(mt, __shfl_xor(mt, 32));
            float mnew = fmaxf(mrun, mt);
            float alpha = __expf(mrun - mnew);
            float rsum = 0.f;
            #pragma unroll
            for (int kf = 0; kf < 4; ++kf)
                #pragma unroll
                for (int r = 0; r < 4; ++r) {
                    float p = __expf(sacc[kf][r] - mnew);
                    sacc[kf][r] = p;
                    rsum += p;
                }
            rsum += __shfl_xor(rsum, 16);
            rsum += __shfl_xor(rsum, 32);
            lrun = lrun * alpha + rsum;
            mrun = mnew;
            #pragma unroll
            for (int df = 0; df < 8; ++df) oacc[df] *= alpha;

            // ---- pack P^T (key order: ks2*32 + {bk*4+r, 16+bk*4+r}) ----
            union { unsigned u[4]; bh8_t v; } bop[2];
            #pragma unroll
            for (int ks2 = 0; ks2 < 2; ++ks2)
                #pragma unroll
                for (int e = 0; e < 8; e += 2) {
                    unsigned lo16 = f2bf(sacc[2 * ks2 + (e >> 2)][e & 3]);
                    unsigned hi16 = f2bf(sacc[2 * ks2 + ((e + 1) >> 2)][(e + 1) & 3]);
                    bop[ks2].u[e >> 1] = lo16 | (hi16 << 16);
                }
            // ---- O^T += V^T * P^T ----
            __builtin_amdgcn_s_setprio(1);
            #pragma unroll
            for (int df = 0; df < 8; ++df) {
                int d = df * 16 + lr;
                #pragma unroll
                for (int ks2 = 0; ks2 < 2; ++ks2) {
                    int ab = (d * 128 + ks2 * 64 + bk * 16) ^ ((d & 7) << 4);
                    bh8_t av = *(const bh8_t*)(Vl + ab);
                    oacc[df] = __builtin_amdgcn_mfma_f32_16x16x32_bf16(
                        av, bop[ks2].v, oacc[df], 0, 0, 0);
                }
            }
            __builtin_amdgcn_s_setprio(0);
        }
        asm volatile("" ::: "memory");
        __builtin_amdgcn_s_barrier();
        asm volatile("" ::: "memory");
    }

    // ---- normalize + store bf16 to AO[B*S][D] ----
    float inv = 1.0f / lrun;
    const int b = bh >> 4, h = bh & 15;
    #pragma unroll
    for (int df = 0; df < 8; ++df) {
        ushort4 o;
        o.x = f2bf(oacc[df][0] * inv);
        o.y = f2bf(oacc[df][1] * inv);
        o.z = f2bf(oacc[df][2] * inv);
        o.w = f2bf(oacc[df][3] * inv);
        size_t off = ((size_t)(b * 2048 + qrow)) * 2048 + h * 128 + df * 16 + bk * 4;
        *(ushort4*)&AO[off] = o;
    }
}

// ---------------------------------------------------------------------------
// Out projection: out[4096][2048] = AO * owtb^T + b (f32 out),
// double-buffered gl_lds prefetch + vmcnt(4).
// ---------------------------------------------------------------------------
__global__ __launch_bounds__(256) void out_gemm(const ushort* __restrict__ A,
                                                const ushort* __restrict__ Bt,
                                                const float* __restrict__ bias,
                                                float* __restrict__ out) {
    __shared__ ushort Al[2][128 * 32];
    __shared__ ushort Bl[2][128 * 32];
    const int tid = threadIdx.x;
    const int l = tid & 63, wv = tid >> 6;
    const int lr = l & 15, bk = l >> 4;
    const int wr = wv >> 1, wc = wv & 1;
    const int row0 = blockIdx.x * 128, col0 = blockIdx.y * 128;

    f4_t zero4 = {0.f, 0.f, 0.f, 0.f};
    f4_t acc[4][4];
    #pragma unroll
    for (int i = 0; i < 4; ++i)
        #pragma unroll
        for (int j = 0; j < 4; ++j) acc[i][j] = zero4;

    const int c0 = tid, c1 = tid + 256;
    const ushort* Ap0 = A  + (size_t)(row0 + (c0 >> 2)) * 2048 + (c0 & 3) * 8;
    const ushort* Ap1 = A  + (size_t)(row0 + (c1 >> 2)) * 2048 + (c1 & 3) * 8;
    const ushort* Bp0 = Bt + (size_t)(col0 + (c0 >> 2)) * 2048 + (c0 & 3) * 8;
    const ushort* Bp1 = Bt + (size_t)(col0 + (c1 >> 2)) * 2048 + (c1 & 3) * 8;
    const int d0 = (c0 - l) * 8, d1 = (c1 - l) * 8;

    auto issue = [&](int k0, int buf) {
        gl_lds16(Ap0 + k0, &Al[buf][d0]);
        gl_lds16(Ap1 + k0, &Al[buf][d1]);
        gl_lds16(Bp0 + k0, &Bl[buf][d0]);
        gl_lds16(Bp1 + k0, &Bl[buf][d1]);
    };

    issue(0, 0);
    for (int k0 = 0; k0 < 2048; k0 += 32) {
        const int buf = (k0 >> 5) & 1;
        if (k0 + 32 < 2048) {
            issue(k0 + 32, buf ^ 1);
            asm volatile("s_waitcnt vmcnt(4)" ::: "memory");
        } else {
            asm volatile("s_waitcnt vmcnt(0)" ::: "memory");
        }
        __builtin_amdgcn_s_barrier();
        asm volatile("" ::: "memory");
        bh8_t af[4], bf[4];
        #pragma unroll
        for (int mf = 0; mf < 4; ++mf)
            af[mf] = *(const bh8_t*)&Al[buf][(wr * 64 + mf * 16 + lr) * 32 + bk * 8];
        #pragma unroll
        for (int nf = 0; nf < 4; ++nf)
            bf[nf] = *(const bh8_t*)&Bl[buf][(wc * 64 + nf * 16 + lr) * 32 + bk * 8];
        __builtin_amdgcn_s_setprio(1);
        #pragma unroll
        for (int mf = 0; mf < 4; ++mf)
            #pragma unroll
            for (int nf = 0; nf < 4; ++nf)
                acc[mf][nf] = __builtin_amdgcn_mfma_f32_16x16x32_bf16(
                    af[mf], bf[nf], acc[mf][nf], 0, 0, 0);
        __builtin_amdgcn_s_setprio(0);
        asm volatile("" ::: "memory");
        __builtin_amdgcn_s_barrier();
        asm volatile("" ::: "memory");
    }

    #pragma unroll
    for (int nf = 0; nf < 4; ++nf) {
        int n = col0 + wc * 64 + nf * 16 + lr;
        float bv = bias[n];
        #pragma unroll
        for (int mf = 0; mf < 4; ++mf) {
            int mbase = row0 + wr * 64 + mf * 16 + bk * 4;
            #pragma unroll
            for (int r = 0; r < 4; ++r)
                out[(size_t)(mbase + r) * 2048 + n] = acc[mf][nf][r] + bv;
        }
    }
}

// ---------------------------------------------------------------------------
extern "C" void kernel_launch(void* const* d_in, const int* in_sizes, int n_in,
                              void* d_out, int out_size, void* d_ws, size_t ws_size,
                              hipStream_t stream)
{
    (void)in_sizes; (void)n_in; (void)out_size; (void)ws_size;
    const float* x     = (const float*)d_in[0];
    const float* cosn  = (const float*)d_in[1];
    const float* sinn  = (const float*)d_in[2];
    const float* qkv_w = (const float*)d_in[3];
    const float* qkv_b = (const float*)d_in[4];
    const float* out_w = (const float*)d_in[5];
    const float* out_b = (const float*)d_in[6];

    char* ws = (char*)d_ws;
    ushort* xb   = (ushort*)(ws);                          // 16 MB [4096][2048]
    ushort* wtb  = (ushort*)(ws + ((size_t)16 << 20));     // 24 MB [6144][2048]
    ushort* owtb = (ushort*)(ws + ((size_t)40 << 20));     //  8 MB [2048][2048]
    ushort* Qb   = (ushort*)(ws + ((size_t)48 << 20));     // 16 MB head-major
    ushort* Kb   = (ushort*)(ws + ((size_t)64 << 20));     // 16 MB head-major
    ushort* Vtg  = (ushort*)(ws + ((size_t)80 << 20));     // 16 MB [bh][d][s']
    ushort* AO   = (ushort*)(ws + ((size_t)96 << 20));     // 16 MB [4096][2048]

    hipLaunchKernelGGL(cvt_f32_bf16, dim3(4096), dim3(256), 0, stream, x, xb);
    hipLaunchKernelGGL(transp_f32_bf16, dim3(96, 32), dim3(256), 0, stream,
                       qkv_w, wtb, 2048, 6144);
    hipLaunchKernelGGL(transp_f32_bf16, dim3(32, 32), dim3(256), 0, stream,
                       out_w, owtb, 2048, 2048);
    hipLaunchKernelGGL(qkv_gemm, dim3(32, 48), dim3(256), 0, stream,
                       xb, wtb, qkv_b, Qb, Kb, Vtg);
    hipLaunchKernelGGL(rope_bf16, dim3(8192), dim3(256), 0, stream,
                       Qb, Kb, cosn, sinn);
    hipLaunchKernelGGL(attn3, dim3(512), dim3(512), 0, stream,
                       Qb, Kb, Vtg, AO);
    hipLaunchKernelGGL(out_gemm, dim3(32, 16), dim3(256), 0, stream,
                       AO, owtb, out_b, (float*)d_out);
}